// Round 1
// baseline (461.187 us; speedup 1.0000x reference)
//
#include <hip/hip_runtime.h>
#include <hip/hip_bf16.h>

typedef __bf16 bf16_8 __attribute__((ext_vector_type(8)));
typedef float f32x4 __attribute__((ext_vector_type(4)));
typedef unsigned short us4 __attribute__((ext_vector_type(4)));

#define AS1(p) ((const __attribute__((address_space(1))) void*)(p))
#define AS3(p) ((__attribute__((address_space(3))) void*)(p))

#define Bb 4
#define Tt 2048
#define Cc 768
#define NH 12
#define HD 64
#define Mrows 8192           // B*T
#define N1 2304              // 3C
#define KDIM 768

__device__ __forceinline__ unsigned short bfbits(float x) {
    __bf16 h = (__bf16)x;
    return __builtin_bit_cast(unsigned short, h);
}

// ---------------- cast x (f32 -> bf16), vectorized ----------------
__global__ __launch_bounds__(256) void cast_f32_bf16(const float* __restrict__ in,
                                                     __bf16* __restrict__ out, int n4) {
    int i = blockIdx.x * blockDim.x + threadIdx.x;
    if (i < n4) {
        float4 v = ((const float4*)in)[i];
        us4 o;
        o.x = bfbits(v.x); o.y = bfbits(v.y); o.z = bfbits(v.z); o.w = bfbits(v.w);
        *(us4*)(out + (size_t)i * 4) = o;
    }
}

// ---------------- transpose-cast: in f32 [R][Cn] -> out bf16 [Cn][R] ----------------
__global__ __launch_bounds__(256) void transpose_cast(const float* __restrict__ in,
                                                      __bf16* __restrict__ out, int R, int Cn) {
    __shared__ float tile[32][33];
    int c0 = blockIdx.x * 32, r0 = blockIdx.y * 32;
    int tx = threadIdx.x, ty = threadIdx.y;
#pragma unroll
    for (int i = 0; i < 4; ++i)
        tile[ty + i * 8][tx] = in[(size_t)(r0 + ty + i * 8) * Cn + c0 + tx];
    __syncthreads();
#pragma unroll
    for (int i = 0; i < 4; ++i)
        out[(size_t)(c0 + ty + i * 8) * R + r0 + tx] = (__bf16)tile[tx][ty + i * 8];
}

// ---------------- bf16 GEMM, B-transposed input ----------------
// C[M][N] = A[M][K] * Bt[N][K]^T + bias
// MODE 0: scatter to q/k [B,H,T,64] and vT [B,H,64,T] (bf16)
// MODE 1: write f32 out [M][N]
template <int MODE>
__global__ __launch_bounds__(256) void gemm_bt(const __bf16* __restrict__ A,
                                               const __bf16* __restrict__ Bt,
                                               const float* __restrict__ bias,
                                               float* __restrict__ outf,
                                               __bf16* __restrict__ qb,
                                               __bf16* __restrict__ kb,
                                               __bf16* __restrict__ vTb,
                                               int M, int N, int K) {
    __shared__ __bf16 As[128 * 32];
    __shared__ __bf16 Bs[128 * 32];
    int tid = threadIdx.x;
    int w = tid >> 6, l = tid & 63, lr = l & 15, lg = l >> 4;
    int wm = w >> 1, wn = w & 1;
    int m0 = blockIdx.x * 128, n0 = blockIdx.y * 128;

    f32x4 acc[4][4] = {};

    for (int kk = 0; kk < K; kk += 32) {
#pragma unroll
        for (int i = 0; i < 2; ++i) {
            int c = (w * 2 + i) * 64 + l;       // 16B-chunk index within 8KB tile
            int row = c >> 2, kc = (c & 3) << 3;
            __builtin_amdgcn_global_load_lds(AS1(A + (size_t)(m0 + row) * K + kk + kc),
                                             AS3(As + (w * 2 + i) * 512), 16, 0, 0);
            __builtin_amdgcn_global_load_lds(AS1(Bt + (size_t)(n0 + row) * K + kk + kc),
                                             AS3(Bs + (w * 2 + i) * 512), 16, 0, 0);
        }
        __syncthreads();
        bf16_8 af[4], bfr[4];
#pragma unroll
        for (int mi = 0; mi < 4; ++mi)
            af[mi] = *(const bf16_8*)&As[(wm * 64 + mi * 16 + lr) * 32 + lg * 8];
#pragma unroll
        for (int ni = 0; ni < 4; ++ni)
            bfr[ni] = *(const bf16_8*)&Bs[(wn * 64 + ni * 16 + lr) * 32 + lg * 8];
#pragma unroll
        for (int mi = 0; mi < 4; ++mi)
#pragma unroll
            for (int ni = 0; ni < 4; ++ni)
                acc[mi][ni] = __builtin_amdgcn_mfma_f32_16x16x32_bf16(af[mi], bfr[ni],
                                                                      acc[mi][ni], 0, 0, 0);
        __syncthreads();
    }

#pragma unroll
    for (int ni = 0; ni < 4; ++ni) {
        int gn = n0 + wn * 64 + ni * 16 + lr;
        float bv = bias[gn];
#pragma unroll
        for (int mi = 0; mi < 4; ++mi) {
            int gm0 = m0 + wm * 64 + mi * 16 + lg * 4;
            f32x4 v = acc[mi][ni];
            if (MODE == 1) {
#pragma unroll
                for (int r = 0; r < 4; ++r)
                    outf[(size_t)(gm0 + r) * N + gn] = v[r] + bv;
            } else {
                int seg = gn / Cc;
                int rem = gn - seg * Cc;
                int h = rem >> 6, d = rem & 63;
                int b = gm0 >> 11, t = gm0 & 2047;
                size_t bh = (size_t)b * NH + h;
                if (seg < 2) {
                    __bf16* dst = (seg ? kb : qb) + (bh * Tt + t) * HD + d;
#pragma unroll
                    for (int r = 0; r < 4; ++r)
                        dst[(size_t)r * HD] = (__bf16)(v[r] + bv);
                } else {
                    us4 pk;
#pragma unroll
                    for (int r = 0; r < 4; ++r) pk[r] = bfbits(v[r] + bv);
                    *(us4*)(vTb + (bh * HD + d) * Tt + t) = pk;
                }
            }
        }
    }
}

// ---------------- flash attention (causal), bf16 MFMA ----------------
// q,k: [B*H][T][64] bf16 ; vT: [B*H][64][T] bf16 ; out: [B][T][C] bf16
__global__ __launch_bounds__(256) void attn_fwd(const __bf16* __restrict__ q,
                                                const __bf16* __restrict__ k,
                                                const __bf16* __restrict__ vT,
                                                __bf16* __restrict__ aout) {
    __shared__ __bf16 plds[4][16 * 64];
    const float NEGINF = -__builtin_inff();
    int blk = blockIdx.x;
    int qt = blk & 31;          // T/64 = 32 q-tiles
    int bh = blk >> 5;
    int w = threadIdx.x >> 6, l = threadIdx.x & 63, lr = l & 15, lg = l >> 4;
    int q0 = qt * 64 + w * 16;  // this wave's q-row base

    const __bf16* qp = q + (size_t)bh * Tt * HD;
    const __bf16* kp = k + (size_t)bh * Tt * HD;
    const __bf16* vp = vT + (size_t)bh * HD * Tt;

    bf16_8 qf[2];
#pragma unroll
    for (int ks = 0; ks < 2; ++ks)
        qf[ks] = *(const bf16_8*)(qp + (size_t)(q0 + lr) * HD + ks * 32 + lg * 8);

    f32x4 accO[4] = {};
    float mcur[4], scur[4];
#pragma unroll
    for (int r = 0; r < 4; ++r) { mcur[r] = NEGINF; scur[r] = 0.f; }

    int lastkt = (q0 + 15) >> 6;
    for (int kt = 0; kt <= lastkt; ++kt) {
        int kbase = kt * 64;
        f32x4 accS[4] = {};
#pragma unroll
        for (int nt = 0; nt < 4; ++nt) {
#pragma unroll
            for (int ks = 0; ks < 2; ++ks) {
                bf16_8 kf = *(const bf16_8*)(kp + (size_t)(kbase + nt * 16 + lr) * HD + ks * 32 + lg * 8);
                accS[nt] = __builtin_amdgcn_mfma_f32_16x16x32_bf16(qf[ks], kf, accS[nt], 0, 0, 0);
            }
        }
        float al[4];
#pragma unroll
        for (int r = 0; r < 4; ++r) {
            int qg = q0 + lg * 4 + r;
            float mx = NEGINF;
#pragma unroll
            for (int nt = 0; nt < 4; ++nt) {
                int kg = kbase + nt * 16 + lr;
                float sv = accS[nt][r] * 0.125f;
                if (kg > qg) sv = NEGINF;
                accS[nt][r] = sv;
                mx = fmaxf(mx, sv);
            }
#pragma unroll
            for (int off = 1; off < 16; off <<= 1)
                mx = fmaxf(mx, __shfl_xor(mx, off));
            float mnew = fmaxf(mcur[r], mx);
            al[r] = __expf(mcur[r] - mnew);
            mcur[r] = mnew;
            float ss = 0.f;
#pragma unroll
            for (int nt = 0; nt < 4; ++nt) {
                float p = __expf(accS[nt][r] - mnew);
                accS[nt][r] = p;
                ss += p;
            }
#pragma unroll
            for (int off = 1; off < 16; off <<= 1)
                ss += __shfl_xor(ss, off);
            scur[r] = scur[r] * al[r] + ss;
        }
#pragma unroll
        for (int dt = 0; dt < 4; ++dt)
#pragma unroll
            for (int r = 0; r < 4; ++r)
                accO[dt][r] *= al[r];
        // P tile -> LDS (bf16), then back in A-fragment layout
#pragma unroll
        for (int nt = 0; nt < 4; ++nt)
#pragma unroll
            for (int r = 0; r < 4; ++r)
                plds[w][(lg * 4 + r) * 64 + nt * 16 + lr] = (__bf16)accS[nt][r];
        bf16_8 pf[2];
#pragma unroll
        for (int ks = 0; ks < 2; ++ks)
            pf[ks] = *(const bf16_8*)&plds[w][lr * 64 + ks * 32 + lg * 8];
#pragma unroll
        for (int dt = 0; dt < 4; ++dt) {
#pragma unroll
            for (int ks = 0; ks < 2; ++ks) {
                bf16_8 vf = *(const bf16_8*)(vp + (size_t)(dt * 16 + lr) * Tt + kbase + ks * 32 + lg * 8);
                accO[dt] = __builtin_amdgcn_mfma_f32_16x16x32_bf16(pf[ks], vf, accO[dt], 0, 0, 0);
            }
        }
    }

    int b = bh / NH, h = bh - b * NH;
#pragma unroll
    for (int r = 0; r < 4; ++r) {
        float inv = 1.0f / scur[r];
        size_t row = (size_t)(b * Tt + q0 + lg * 4 + r) * Cc + h * HD;
#pragma unroll
        for (int dt = 0; dt < 4; ++dt)
            aout[row + dt * 16 + lr] = (__bf16)(accO[dt][r] * inv);
    }
}

// ---------------- launch ----------------
extern "C" void kernel_launch(void* const* d_in, const int* in_sizes, int n_in,
                              void* d_out, int out_size, void* d_ws, size_t ws_size,
                              hipStream_t stream) {
    const float* x      = (const float*)d_in[0];
    const float* w_attn = (const float*)d_in[1];
    const float* b_attn = (const float*)d_in[2];
    const float* w_proj = (const float*)d_in[3];
    const float* b_proj = (const float*)d_in[4];
    float* out = (float*)d_out;

    char* ws = (char*)d_ws;
    constexpr size_t SZ_XB   = (size_t)Mrows * KDIM * 2;   // 12.6 MB
    constexpr size_t SZ_WAT  = (size_t)N1 * KDIM * 2;      // 3.5 MB
    constexpr size_t SZ_WPT  = (size_t)Cc * Cc * 2;        // 1.2 MB
    constexpr size_t SZ_HEAD = (size_t)Bb * NH * Tt * HD * 2;  // 12.6 MB
    __bf16* xb  = (__bf16*)ws;
    __bf16* wat = (__bf16*)(ws + SZ_XB);
    __bf16* wpt = (__bf16*)(ws + SZ_XB + SZ_WAT);
    __bf16* qb  = (__bf16*)(ws + SZ_XB + SZ_WAT + SZ_WPT);
    __bf16* kb  = (__bf16*)(ws + SZ_XB + SZ_WAT + SZ_WPT + SZ_HEAD);
    __bf16* vTb = (__bf16*)(ws + SZ_XB + SZ_WAT + SZ_WPT + 2 * SZ_HEAD);
    __bf16* ao  = (__bf16*)(ws + SZ_XB + SZ_WAT + SZ_WPT + 3 * SZ_HEAD);

    // 1. casts
    cast_f32_bf16<<<(Mrows * KDIM / 4 + 255) / 256, 256, 0, stream>>>(x, xb, Mrows * KDIM / 4);
    transpose_cast<<<dim3(N1 / 32, KDIM / 32), dim3(32, 8), 0, stream>>>(w_attn, wat, KDIM, N1);
    transpose_cast<<<dim3(Cc / 32, Cc / 32), dim3(32, 8), 0, stream>>>(w_proj, wpt, Cc, Cc);

    // 2. QKV GEMM + head scatter
    gemm_bt<0><<<dim3(Mrows / 128, N1 / 128), 256, 0, stream>>>(
        xb, wat, b_attn, nullptr, qb, kb, vTb, Mrows, N1, KDIM);

    // 3. flash attention
    attn_fwd<<<Bb * NH * (Tt / 64), 256, 0, stream>>>(qb, kb, vTb, ao);

    // 4. projection GEMM
    gemm_bt<1><<<dim3(Mrows / 128, Cc / 128), 256, 0, stream>>>(
        ao, wpt, b_proj, out, nullptr, nullptr, nullptr, Mrows, Cc, KDIM);
}

// Round 2
// 187.542 us; speedup vs baseline: 2.4591x; 2.4591x over previous
//
#include <hip/hip_runtime.h>
#include <hip/hip_bf16.h>

typedef __bf16 bf16_8 __attribute__((ext_vector_type(8)));
typedef float f32x4 __attribute__((ext_vector_type(4)));
typedef unsigned short us4 __attribute__((ext_vector_type(4)));

#define AS1(p) ((const __attribute__((address_space(1))) void*)(p))
#define AS3(p) ((__attribute__((address_space(3))) void*)(p))

#define Bb 4
#define Tt 2048
#define Cc 768
#define NH 12
#define HD 64
#define Mrows 8192           // B*T
#define N1 2304              // 3C
#define KDIM 768
#define PSTR 72              // P LDS row stride (elements); 144B = 9*16B

__device__ __forceinline__ unsigned short bfbits(float x) {
    __bf16 h = (__bf16)x;
    return __builtin_bit_cast(unsigned short, h);
}

// ---------------- cast x (f32 -> bf16), vectorized ----------------
__global__ __launch_bounds__(256) void cast_f32_bf16(const float* __restrict__ in,
                                                     __bf16* __restrict__ out, int n4) {
    int i = blockIdx.x * blockDim.x + threadIdx.x;
    if (i < n4) {
        float4 v = ((const float4*)in)[i];
        us4 o;
        o.x = bfbits(v.x); o.y = bfbits(v.y); o.z = bfbits(v.z); o.w = bfbits(v.w);
        *(us4*)(out + (size_t)i * 4) = o;
    }
}

// ---------------- transpose-cast: in f32 [R][Cn] -> out bf16 [Cn][R] ----------------
__global__ __launch_bounds__(256) void transpose_cast(const float* __restrict__ in,
                                                      __bf16* __restrict__ out, int R, int Cn) {
    __shared__ float tile[32][33];
    int c0 = blockIdx.x * 32, r0 = blockIdx.y * 32;
    int tx = threadIdx.x, ty = threadIdx.y;
#pragma unroll
    for (int i = 0; i < 4; ++i)
        tile[ty + i * 8][tx] = in[(size_t)(r0 + ty + i * 8) * Cn + c0 + tx];
    __syncthreads();
#pragma unroll
    for (int i = 0; i < 4; ++i)
        out[(size_t)(c0 + ty + i * 8) * R + r0 + tx] = (__bf16)tile[tx][ty + i * 8];
}

// ---------------- bf16 GEMM, B-transposed input ----------------
template <int MODE>
__global__ __launch_bounds__(256) void gemm_bt(const __bf16* __restrict__ A,
                                               const __bf16* __restrict__ Bt,
                                               const float* __restrict__ bias,
                                               float* __restrict__ outf,
                                               __bf16* __restrict__ qb,
                                               __bf16* __restrict__ kb,
                                               __bf16* __restrict__ vTb,
                                               int M, int N, int K) {
    __shared__ __bf16 As[128 * 32];
    __shared__ __bf16 Bs[128 * 32];
    int tid = threadIdx.x;
    int w = tid >> 6, l = tid & 63, lr = l & 15, lg = l >> 4;
    int wm = w >> 1, wn = w & 1;
    int m0 = blockIdx.x * 128, n0 = blockIdx.y * 128;

    f32x4 acc[4][4] = {};

    for (int kk = 0; kk < K; kk += 32) {
#pragma unroll
        for (int i = 0; i < 2; ++i) {
            int c = (w * 2 + i) * 64 + l;
            int row = c >> 2, kc = (c & 3) << 3;
            __builtin_amdgcn_global_load_lds(AS1(A + (size_t)(m0 + row) * K + kk + kc),
                                             AS3(As + (w * 2 + i) * 512), 16, 0, 0);
            __builtin_amdgcn_global_load_lds(AS1(Bt + (size_t)(n0 + row) * K + kk + kc),
                                             AS3(Bs + (w * 2 + i) * 512), 16, 0, 0);
        }
        __syncthreads();
        bf16_8 af[4], bfr[4];
#pragma unroll
        for (int mi = 0; mi < 4; ++mi)
            af[mi] = *(const bf16_8*)&As[(wm * 64 + mi * 16 + lr) * 32 + lg * 8];
#pragma unroll
        for (int ni = 0; ni < 4; ++ni)
            bfr[ni] = *(const bf16_8*)&Bs[(wn * 64 + ni * 16 + lr) * 32 + lg * 8];
#pragma unroll
        for (int mi = 0; mi < 4; ++mi)
#pragma unroll
            for (int ni = 0; ni < 4; ++ni)
                acc[mi][ni] = __builtin_amdgcn_mfma_f32_16x16x32_bf16(af[mi], bfr[ni],
                                                                      acc[mi][ni], 0, 0, 0);
        __syncthreads();
    }

#pragma unroll
    for (int ni = 0; ni < 4; ++ni) {
        int gn = n0 + wn * 64 + ni * 16 + lr;
        float bv = bias[gn];
#pragma unroll
        for (int mi = 0; mi < 4; ++mi) {
            int gm0 = m0 + wm * 64 + mi * 16 + lg * 4;
            f32x4 v = acc[mi][ni];
            if (MODE == 1) {
#pragma unroll
                for (int r = 0; r < 4; ++r)
                    outf[(size_t)(gm0 + r) * N + gn] = v[r] + bv;
            } else {
                int seg = gn / Cc;
                int rem = gn - seg * Cc;
                int h = rem >> 6, d = rem & 63;
                int b = gm0 >> 11, t = gm0 & 2047;
                size_t bh = (size_t)b * NH + h;
                if (seg < 2) {
                    __bf16* dst = (seg ? kb : qb) + (bh * Tt + t) * HD + d;
#pragma unroll
                    for (int r = 0; r < 4; ++r)
                        dst[(size_t)r * HD] = (__bf16)(v[r] + bv);
                } else {
                    us4 pk;
#pragma unroll
                    for (int r = 0; r < 4; ++r) pk[r] = bfbits(v[r] + bv);
                    *(us4*)(vTb + (bh * HD + d) * Tt + t) = pk;
                }
            }
        }
    }
}

// ---------------- flash attention v2: LDS-staged, double-buffered, swizzled ----------------
// q,k: [B*H][T][64] bf16 ; vT: [B*H][64][T] bf16 ; out: [B][T][C] bf16
// Block: 128 q-rows (1 bh), 4 waves x 32 rows. KV tile 64.
__global__ __launch_bounds__(256) void attn_fwd(const __bf16* __restrict__ q,
                                                const __bf16* __restrict__ k,
                                                const __bf16* __restrict__ vT,
                                                __bf16* __restrict__ aout) {
    __shared__ __bf16 Ks[2][64 * 64];
    __shared__ __bf16 Vs[2][64 * 64];
    __shared__ __bf16 Ps[4][32 * PSTR];
    const float NEGINF = -__builtin_inff();

    int blk = blockIdx.x;
    int qt = 15 - (blk / 48);        // descending work order (LPT)
    int bh = blk % 48;               // same bh -> same XCD (48 % 8 == 0)
    int tid = threadIdx.x;
    int w = tid >> 6, l = tid & 63, lr = l & 15, lg = l >> 4;
    int q0w = qt * 128 + w * 32;

    const __bf16* qp = q + (size_t)bh * Tt * HD;
    const __bf16* kp = k + (size_t)bh * Tt * HD;
    const __bf16* vp = vT + (size_t)bh * HD * Tt;

    // Q fragments for this wave's 32 rows (2 m-frags), held in regs.
    bf16_8 qf[2][2];
#pragma unroll
    for (int mf = 0; mf < 2; ++mf)
#pragma unroll
        for (int ks = 0; ks < 2; ++ks)
            qf[mf][ks] = *(const bf16_8*)(qp + (size_t)(q0w + mf * 16 + lr) * HD + ks * 32 + lg * 8);

    f32x4 accO[2][4] = {};
    float mcur[2][4], scur[2][4];
#pragma unroll
    for (int mf = 0; mf < 2; ++mf)
#pragma unroll
        for (int r = 0; r < 4; ++r) { mcur[mf][r] = NEGINF; scur[mf][r] = 0.f; }

    const int ntile = 2 * qt + 2;
    // staging: tile is 64 rows x 128B = 512 x 16B chunks; source col-chunk XOR-swizzled by row&7
    auto stage = [&](int buf, int kt) {
        int kbase = kt * 64;
#pragma unroll
        for (int s = 0; s < 2; ++s) {
            int c = s * 256 + tid;
            int row = c >> 3, j = c & 7;
            int js = j ^ (row & 7);
            __builtin_amdgcn_global_load_lds(AS1(kp + (size_t)(kbase + row) * HD + js * 8),
                                             AS3(&Ks[buf][c * 8]), 16, 0, 0);
            __builtin_amdgcn_global_load_lds(AS1(vp + (size_t)row * Tt + kbase + js * 8),
                                             AS3(&Vs[buf][c * 8]), 16, 0, 0);
        }
    };

    stage(0, 0);
    __syncthreads();

    const int swz = lr & 7;
    const int co0 = (lg ^ swz) * 8;
    const int co1 = ((4 + lg) ^ swz) * 8;

    for (int kt = 0; kt < ntile; ++kt) {
        int cur = kt & 1;
        int kbase = kt * 64;
        if (kt + 1 < ntile) stage(cur ^ 1, kt + 1);

        if (kbase <= q0w + 31) {
            const __bf16* Kc = &Ks[cur][0];
            const __bf16* Vc = &Vs[cur][0];
            // ---- QK^T ----
            f32x4 accS[2][4] = {};
#pragma unroll
            for (int nt = 0; nt < 4; ++nt) {
                int rb = (nt * 16 + lr) * 64;
                bf16_8 kf0 = *(const bf16_8*)(Kc + rb + co0);
                bf16_8 kf1 = *(const bf16_8*)(Kc + rb + co1);
                accS[0][nt] = __builtin_amdgcn_mfma_f32_16x16x32_bf16(qf[0][0], kf0, accS[0][nt], 0, 0, 0);
                accS[0][nt] = __builtin_amdgcn_mfma_f32_16x16x32_bf16(qf[0][1], kf1, accS[0][nt], 0, 0, 0);
                accS[1][nt] = __builtin_amdgcn_mfma_f32_16x16x32_bf16(qf[1][0], kf0, accS[1][nt], 0, 0, 0);
                accS[1][nt] = __builtin_amdgcn_mfma_f32_16x16x32_bf16(qf[1][1], kf1, accS[1][nt], 0, 0, 0);
            }
            // ---- online softmax ----
            bool needmask = (kbase + 63 > q0w);
            float al[2][4];
#pragma unroll
            for (int mf = 0; mf < 2; ++mf) {
#pragma unroll
                for (int r = 0; r < 4; ++r) {
                    int qg = q0w + mf * 16 + lg * 4 + r;
                    float mx = NEGINF;
#pragma unroll
                    for (int nt = 0; nt < 4; ++nt) {
                        float sv = accS[mf][nt][r] * 0.125f;
                        if (needmask && (kbase + nt * 16 + lr > qg)) sv = NEGINF;
                        accS[mf][nt][r] = sv;
                        mx = fmaxf(mx, sv);
                    }
#pragma unroll
                    for (int off = 1; off < 16; off <<= 1)
                        mx = fmaxf(mx, __shfl_xor(mx, off));
                    float mnew = fmaxf(mcur[mf][r], mx);
                    al[mf][r] = __expf(mcur[mf][r] - mnew);
                    mcur[mf][r] = mnew;
                    float ss = 0.f;
#pragma unroll
                    for (int nt = 0; nt < 4; ++nt) {
                        float p = __expf(accS[mf][nt][r] - mnew);
                        accS[mf][nt][r] = p;
                        ss += p;
                    }
#pragma unroll
                    for (int off = 1; off < 16; off <<= 1)
                        ss += __shfl_xor(ss, off);
                    scur[mf][r] = scur[mf][r] * al[mf][r] + ss;
                }
            }
#pragma unroll
            for (int mf = 0; mf < 2; ++mf)
#pragma unroll
                for (int dt = 0; dt < 4; ++dt)
#pragma unroll
                    for (int r = 0; r < 4; ++r)
                        accO[mf][dt][r] *= al[mf][r];
            // ---- P -> LDS (bf16) -> A-frags ----
#pragma unroll
            for (int mf = 0; mf < 2; ++mf)
#pragma unroll
                for (int nt = 0; nt < 4; ++nt)
#pragma unroll
                    for (int r = 0; r < 4; ++r)
                        Ps[w][(mf * 16 + lg * 4 + r) * PSTR + nt * 16 + lr] = (__bf16)accS[mf][nt][r];
            bf16_8 pf[2][2];
#pragma unroll
            for (int mf = 0; mf < 2; ++mf)
#pragma unroll
                for (int ks = 0; ks < 2; ++ks)
                    pf[mf][ks] = *(const bf16_8*)&Ps[w][(mf * 16 + lr) * PSTR + ks * 32 + lg * 8];
            // ---- PV ----
#pragma unroll
            for (int dt = 0; dt < 4; ++dt) {
                int rb = (dt * 16 + lr) * 64;
                bf16_8 vf0 = *(const bf16_8*)(Vc + rb + co0);
                bf16_8 vf1 = *(const bf16_8*)(Vc + rb + co1);
                accO[0][dt] = __builtin_amdgcn_mfma_f32_16x16x32_bf16(pf[0][0], vf0, accO[0][dt], 0, 0, 0);
                accO[0][dt] = __builtin_amdgcn_mfma_f32_16x16x32_bf16(pf[0][1], vf1, accO[0][dt], 0, 0, 0);
                accO[1][dt] = __builtin_amdgcn_mfma_f32_16x16x32_bf16(pf[1][0], vf0, accO[1][dt], 0, 0, 0);
                accO[1][dt] = __builtin_amdgcn_mfma_f32_16x16x32_bf16(pf[1][1], vf1, accO[1][dt], 0, 0, 0);
            }
        }
        __syncthreads();
    }

    int b = bh / NH, h = bh - b * NH;
#pragma unroll
    for (int mf = 0; mf < 2; ++mf)
#pragma unroll
        for (int r = 0; r < 4; ++r) {
            float inv = 1.0f / scur[mf][r];
            size_t row = (size_t)(b * Tt + q0w + mf * 16 + lg * 4 + r) * Cc + h * HD;
#pragma unroll
            for (int dt = 0; dt < 4; ++dt)
                aout[row + dt * 16 + lr] = (__bf16)(accO[mf][dt][r] * inv);
        }
}

// ---------------- launch ----------------
extern "C" void kernel_launch(void* const* d_in, const int* in_sizes, int n_in,
                              void* d_out, int out_size, void* d_ws, size_t ws_size,
                              hipStream_t stream) {
    const float* x      = (const float*)d_in[0];
    const float* w_attn = (const float*)d_in[1];
    const float* b_attn = (const float*)d_in[2];
    const float* w_proj = (const float*)d_in[3];
    const float* b_proj = (const float*)d_in[4];
    float* out = (float*)d_out;

    char* ws = (char*)d_ws;
    constexpr size_t SZ_XB   = (size_t)Mrows * KDIM * 2;
    constexpr size_t SZ_WAT  = (size_t)N1 * KDIM * 2;
    constexpr size_t SZ_WPT  = (size_t)Cc * Cc * 2;
    constexpr size_t SZ_HEAD = (size_t)Bb * NH * Tt * HD * 2;
    __bf16* xb  = (__bf16*)ws;
    __bf16* wat = (__bf16*)(ws + SZ_XB);
    __bf16* wpt = (__bf16*)(ws + SZ_XB + SZ_WAT);
    __bf16* qb  = (__bf16*)(ws + SZ_XB + SZ_WAT + SZ_WPT);
    __bf16* kb  = (__bf16*)(ws + SZ_XB + SZ_WAT + SZ_WPT + SZ_HEAD);
    __bf16* vTb = (__bf16*)(ws + SZ_XB + SZ_WAT + SZ_WPT + 2 * SZ_HEAD);
    __bf16* ao  = (__bf16*)(ws + SZ_XB + SZ_WAT + SZ_WPT + 3 * SZ_HEAD);

    cast_f32_bf16<<<(Mrows * KDIM / 4 + 255) / 256, 256, 0, stream>>>(x, xb, Mrows * KDIM / 4);
    transpose_cast<<<dim3(N1 / 32, KDIM / 32), dim3(32, 8), 0, stream>>>(w_attn, wat, KDIM, N1);
    transpose_cast<<<dim3(Cc / 32, Cc / 32), dim3(32, 8), 0, stream>>>(w_proj, wpt, Cc, Cc);

    gemm_bt<0><<<dim3(Mrows / 128, N1 / 128), 256, 0, stream>>>(
        xb, wat, b_attn, nullptr, qb, kb, vTb, Mrows, N1, KDIM);

    attn_fwd<<<48 * 16, 256, 0, stream>>>(qb, kb, vTb, ao);

    gemm_bt<1><<<dim3(Mrows / 128, Cc / 128), 256, 0, stream>>>(
        ao, wpt, b_proj, out, nullptr, nullptr, nullptr, Mrows, Cc, KDIM);
}